// Round 9
// baseline (1272.228 us; speedup 1.0000x reference)
//
#include <hip/hip_runtime.h>
#include <math.h>

#define BATCH 32
#define SEQ   4096
#define DM    256
#define NS    64
#define TSTEP 16   // time steps per staged LDS tile

// z-space recurrence: z = a*z + u, x = B_tilde * z exactly.
// y = sum_n (C*B_tilde)[n] * z[n].
// chain = one (b,d) recurrence. 4 lanes per chain, 16 states per lane.
// wave = 64 lanes = 16 chains = (one b, 16 consecutive d).
// Single-kernel decoupled-lookback fusion (r8's cg::sync was refused at
// runtime -> fallback; this round replaces it with rocPRIM-style manual
// sync that works under graph capture):
//   - vbid from a global atomic counter => spin-waiters only ever wait on
//     lower vbids (resident or done) => deadlock-free, no residency assumption
//   - per-chunk completion counts with threadfence/acquire ordering
//   - phase2 (chunk combine) folded in-register; pass2 kernel eliminated
// Flags (counts[16] + vbid counter) live at ws + C*2MB, zeroed by a
// capturable hipMemsetAsync each launch.

__global__ __launch_bounds__(256, 2)
void fused_kernel(const float* __restrict__ u,
                  const float* __restrict__ log_dt,
                  const float* __restrict__ A_real,
                  const float* __restrict__ B,
                  const float* __restrict__ Cm,
                  float* __restrict__ S,
                  const float* __restrict__ x0,
                  float* __restrict__ y,
                  unsigned int* __restrict__ flags,  // [0..15] counts, [31] vbid
                  int Tc, int C) {
    __shared__ float tiles[4][2][TSTEP][16];  // 8 KB: 4 waves x dbuf x tile
    __shared__ int vbid_s;
    if (threadIdx.x == 0)
        vbid_s = (int)atomicAdd(&flags[31], 1u);  // virtual block id
    __syncthreads();
    int vbid = vbid_s;

    int wid  = threadIdx.x >> 6;
    int lane = threadIdx.x & 63;
    int wave = (vbid << 2) | wid;
    int w  = wave & 511;   // chain group within chunk
    int g  = wave >> 9;    // chunk
    int b  = w >> 4;
    int d0 = (w & 15) << 4;
    int c   = lane >> 2;   // chain within wave (0..15)
    int sub = lane & 3;    // quarter of the state vector
    int d   = d0 + c;
    int n0  = sub << 4;

    float dt = expf(log_dt[d]);  // DT_SCALE = 1.0
    const float* Ap = A_real + d * NS + n0;
    float a[16], z[16];
#pragma unroll
    for (int k = 0; k < 16; ++k)
        a[k] = expf(Ap[k] * dt);

    const size_t tadv = (size_t)TSTEP * DM;
    float* slot0 = &tiles[wid][0][0][0] + (lane << 2);  // lane's 16B in buf0
    const int ntiles = Tc / TSTEP;
    const size_t estride = (size_t)BATCH * DM * NS;

    // ---- phase 1: local z-scan from zero; publish end state E_g ----
    if (g < C - 1) {
#pragma unroll
        for (int k = 0; k < 16; ++k) z[k] = 0.0f;
        const float* gsrc = u + (size_t)b * SEQ * DM + (size_t)(g * Tc) * DM
                            + (size_t)(lane >> 2) * DM + d0 + ((lane & 3) << 2);
        float4 rnext = *(const float4*)gsrc;
        *(float4*)slot0 = rnext;
        gsrc += tadv;
        rnext = *(const float4*)gsrc;
        gsrc += tadv;
        for (int tile = 0; tile < ntiles; ++tile) {
            int cur = tile & 1;
            if (tile + 1 < ntiles)
                *(float4*)(slot0 + (((tile + 1) & 1) << 8)) = rnext;
            if (tile + 2 < ntiles) {
                rnext = *(const float4*)gsrc;
                gsrc += tadv;
            }
            const float* tb = &tiles[wid][cur][0][0] + c;
#pragma unroll
            for (int s = 0; s < TSTEP; ++s) {
                float uv = tb[s << 4];          // broadcast ds_read_b32
#pragma unroll
                for (int k = 0; k < 16; ++k)
                    z[k] = fmaf(a[k], z[k], uv);
            }
        }
        float* Sp = S + (((size_t)g * BATCH + b) * DM + d) * NS + n0;
        float4* Sp4 = (float4*)Sp;
#pragma unroll
        for (int j = 0; j < 4; ++j)
            Sp4[j] = make_float4(z[4*j], z[4*j+1], z[4*j+2], z[4*j+3]);
        __threadfence();                        // order E stores before count
        if (lane == 0)
            atomicAdd(&flags[g], 1u);           // device-scope by default
    }

    // ---- phase 2: z = incoming true state via lookback over E_0..E_{g-1} --
    {
        const float* Xp = x0 + d * NS + n0;
        const float* Bp = B + d * NS + n0;
#pragma unroll
        for (int k = 0; k < 16; ++k) {
            float x0v = Xp[k];
            if (x0v == 0.0f) { z[k] = 0.0f; }   // common/bench case
            else {
                float bt = (1.0f - a[k]) * Bp[k] / Ap[k];
                z[k] = (bt != 0.0f) ? (x0v / bt) : 0.0f;
            }
        }
    }
    if (g > 0) {
        float aT[16];
        float dTc = dt * (float)Tc;
#pragma unroll
        for (int k = 0; k < 16; ++k)
            aT[k] = expf(Ap[k] * dTc);          // a^Tc
        const float* Eb = S + ((size_t)b * DM + d) * NS + n0;
        for (int h = 0; h < g; ++h) {
            // spin until all 512 waves of chunk h have published
            while (__hip_atomic_load(&flags[h], __ATOMIC_ACQUIRE,
                                     __HIP_MEMORY_SCOPE_AGENT) < 512u)
                __builtin_amdgcn_s_sleep(2);
            const float4* E4 = (const float4*)(Eb + (size_t)h * estride);
#pragma unroll
            for (int j = 0; j < 4; ++j) {
                float4 v = E4[j];
                z[4*j]   = fmaf(aT[4*j],   z[4*j],   v.x);
                z[4*j+1] = fmaf(aT[4*j+1], z[4*j+1], v.y);
                z[4*j+2] = fmaf(aT[4*j+2], z[4*j+2], v.z);
                z[4*j+3] = fmaf(aT[4*j+3], z[4*j+3], v.w);
            }
        }
    }

    // ---- phase 3: full scan from true incoming state, emit y ----
    float cbt[16];
    {
        const float* Bp = B + d * NS + n0;
        const float* Cp = Cm + d * NS + n0;
#pragma unroll
        for (int k = 0; k < 16; ++k)
            cbt[k] = Cp[k] * ((1.0f - a[k]) * Bp[k] / Ap[k]);  // C * B_tilde
    }
    const float* gsrc = u + (size_t)b * SEQ * DM + (size_t)(g * Tc) * DM
                        + (size_t)(lane >> 2) * DM + d0 + ((lane & 3) << 2);
    float* yptr = y + (size_t)b * SEQ * DM + (size_t)(g * Tc) * DM + d;

    float4 rnext = *(const float4*)gsrc;
    *(float4*)slot0 = rnext;
    gsrc += tadv;
    rnext = *(const float4*)gsrc;
    gsrc += tadv;

    for (int tile = 0; tile < ntiles; ++tile) {
        int cur = tile & 1;
        if (tile + 1 < ntiles)
            *(float4*)(slot0 + (((tile + 1) & 1) << 8)) = rnext;
        if (tile + 2 < ntiles) {
            rnext = *(const float4*)gsrc;
            gsrc += tadv;
        }
        const float* tb = &tiles[wid][cur][0][0] + c;
#pragma unroll
        for (int s = 0; s < TSTEP; ++s) {
            float uv = tb[s << 4];              // broadcast ds_read_b32
            float p0 = 0.0f, p1 = 0.0f;
#pragma unroll
            for (int k = 0; k < 16; k += 2) {
                z[k]   = fmaf(a[k],   z[k],   uv); p0 = fmaf(cbt[k],   z[k],   p0);
                z[k+1] = fmaf(a[k+1], z[k+1], uv); p1 = fmaf(cbt[k+1], z[k+1], p1);
            }
            float p = p0 + p1;
            p += __shfl_xor(p, 1);   // combine the four quarter-state partials
            p += __shfl_xor(p, 2);
            if (sub == 0) yptr[s * DM] = p;
        }
        yptr += tadv;
    }
}

// ---------------- C==1 fallback: single full-sequence scan ----------------
__global__ __launch_bounds__(256, 2)
void scan1_kernel(const float* __restrict__ u,
                  const float* __restrict__ log_dt,
                  const float* __restrict__ A_real,
                  const float* __restrict__ B,
                  const float* __restrict__ Cm,
                  const float* __restrict__ x0,
                  float* __restrict__ y, int Tc) {
    __shared__ float tiles[4][2][TSTEP][16];
    int wid  = threadIdx.x >> 6;
    int lane = threadIdx.x & 63;
    int wave = (blockIdx.x * blockDim.x + threadIdx.x) >> 6;
    int w  = wave & 511;
    int b  = w >> 4;
    int d0 = (w & 15) << 4;
    int c   = lane >> 2;
    int sub = lane & 3;
    int d   = d0 + c;
    int n0  = sub << 4;

    float a[16], cbt[16], z[16];
    {
        float dt = expf(log_dt[d]);
        const float* Ap = A_real + d * NS + n0;
        const float* Bp = B + d * NS + n0;
        const float* Cp = Cm + d * NS + n0;
        const float* Xp = x0 + d * NS + n0;
#pragma unroll
        for (int k = 0; k < 16; ++k) {
            float ar = Ap[k];
            float at = expf(ar * dt);
            a[k] = at;
            float bt = (1.0f - at) * Bp[k] / ar;
            cbt[k] = Cp[k] * bt;
            float x0v = Xp[k];
            z[k] = (x0v == 0.0f) ? 0.0f : ((bt != 0.0f) ? (x0v / bt) : 0.0f);
        }
    }
    const float* gsrc = u + (size_t)b * SEQ * DM
                        + (size_t)(lane >> 2) * DM + d0 + ((lane & 3) << 2);
    const size_t tadv = (size_t)TSTEP * DM;
    float* slot0 = &tiles[wid][0][0][0] + (lane << 2);
    const int ntiles = Tc / TSTEP;
    float* yptr = y + (size_t)b * SEQ * DM + d;

    float4 rnext = *(const float4*)gsrc;
    *(float4*)slot0 = rnext;
    gsrc += tadv;
    rnext = *(const float4*)gsrc;
    gsrc += tadv;

    for (int tile = 0; tile < ntiles; ++tile) {
        int cur = tile & 1;
        if (tile + 1 < ntiles)
            *(float4*)(slot0 + (((tile + 1) & 1) << 8)) = rnext;
        if (tile + 2 < ntiles) {
            rnext = *(const float4*)gsrc;
            gsrc += tadv;
        }
        const float* tb = &tiles[wid][cur][0][0] + c;
#pragma unroll
        for (int s = 0; s < TSTEP; ++s) {
            float uv = tb[s << 4];
            float p0 = 0.0f, p1 = 0.0f;
#pragma unroll
            for (int k = 0; k < 16; k += 2) {
                z[k]   = fmaf(a[k],   z[k],   uv); p0 = fmaf(cbt[k],   z[k],   p0);
                z[k+1] = fmaf(a[k+1], z[k+1], uv); p1 = fmaf(cbt[k+1], z[k+1], p1);
            }
            float p = p0 + p1;
            p += __shfl_xor(p, 1);
            p += __shfl_xor(p, 2);
            if (sub == 0) yptr[s * DM] = p;
        }
        yptr += tadv;
    }
}

extern "C" void kernel_launch(void* const* d_in, const int* in_sizes, int n_in,
                              void* d_out, int out_size, void* d_ws, size_t ws_size,
                              hipStream_t stream) {
    const float* u      = (const float*)d_in[0];
    const float* log_dt = (const float*)d_in[1];
    const float* A_real = (const float*)d_in[2];
    const float* B      = (const float*)d_in[3];
    const float* Cm     = (const float*)d_in[4];
    const float* x0     = (const float*)d_in[5];
    float* y = (float*)d_out;
    float* S = (float*)d_ws;

    const size_t per_chunk = (size_t)BATCH * DM * NS * sizeof(float);  // 2 MB
    int C = 16;
    while (C > 1 && (size_t)C * per_chunk + 256 > ws_size) C >>= 1;
    if ((size_t)C * per_chunk + 256 > ws_size) C = 1;
    int Tc = SEQ / C;

    if (C > 1) {
        unsigned int* flags =
            (unsigned int*)((char*)d_ws + (size_t)C * per_chunk);
        hipMemsetAsync(flags, 0, 32 * sizeof(unsigned int), stream);
        fused_kernel<<<dim3(C * 128), dim3(256), 0, stream>>>(
            u, log_dt, A_real, B, Cm, S, x0, y, flags, Tc, C);
    } else {
        scan1_kernel<<<dim3(128), dim3(256), 0, stream>>>(
            u, log_dt, A_real, B, Cm, x0, y, Tc);
    }
}

// Round 10
// 401.657 us; speedup vs baseline: 3.1675x; 3.1675x over previous
//
#include <hip/hip_runtime.h>
#include <math.h>

#define BATCH 32
#define SEQ   4096
#define DM    256
#define NS    64
#define TSTEP 16   // time steps per staged LDS tile

// z-space recurrence: z = a*z + u, x = B_tilde * z exactly.
// y = sum_n (C*B_tilde)[n] * z[n].
// chain = one (b,d) recurrence. 4 lanes per chain, 16 states per lane.
// wave = 64 lanes = 16 chains = (one b, 16 consecutive d).
// Two kernels:
//   pass1: local z-scan per chunk (chunks 0..C-2), publish end state E_g.
//          Depth-3 LDS tile pipeline (2 VMEM in flight) - it has half the
//          FMA latency-cover of pass3.
//   pass3: per-wave in-register lookback over E_0..E_{g-1} (replaces the
//          old pass2 kernel; the pass1->pass3 kernel boundary provides the
//          sync), then full scan emitting y.
// r9 lesson: in-kernel grid sync without guaranteed residency collapses
// into generation-serialized spinning (1127us). Kernel boundaries only.

// ---------------- pass 1 ----------------
__global__ __launch_bounds__(256, 2)
void pass1_kernel(const float* __restrict__ u,
                  const float* __restrict__ log_dt,
                  const float* __restrict__ A_real,
                  float* __restrict__ S, int Tc) {
    __shared__ float tiles[4][2][TSTEP][16];  // 8 KB: 4 waves x dbuf x tile
    int wid  = threadIdx.x >> 6;
    int lane = threadIdx.x & 63;
    int wave = (blockIdx.x * blockDim.x + threadIdx.x) >> 6;
    int w  = wave & 511;   // chain group within chunk
    int g  = wave >> 9;    // chunk
    int b  = w >> 4;
    int d0 = (w & 15) << 4;
    int c   = lane >> 2;   // chain within wave (0..15)
    int sub = lane & 3;    // quarter of the state vector
    int d   = d0 + c;
    int n0  = sub << 4;

    float a[16], z[16];
    {
        float dt = expf(log_dt[d]);  // DT_SCALE = 1.0
        const float* Ap = A_real + d * NS + n0;
#pragma unroll
        for (int k = 0; k < 16; ++k) {
            a[k] = expf(Ap[k] * dt);
            z[k] = 0.0f;
        }
    }

    // staging: lane L loads u[t0 + (L>>2)][d0 + (L&3)*4 .. +3] (float4)
    const float* gsrc = u + (size_t)b * SEQ * DM + (size_t)(g * Tc) * DM
                        + (size_t)(lane >> 2) * DM + d0 + ((lane & 3) << 2);
    const size_t tadv = (size_t)TSTEP * DM;
    float* slot0 = &tiles[wid][0][0][0] + (lane << 2);  // lane's 16B in buf0
    const int ntiles = Tc / TSTEP;   // >= 16 whenever pass1 launches

    // depth-3 pipeline: tile0 staged; rA=tile1, rB=tile2 in flight
    float4 r0 = *(const float4*)gsrc;
    *(float4*)slot0 = r0;
    float4 rA = *(const float4*)(gsrc + tadv);
    float4 rB = *(const float4*)(gsrc + 2 * tadv);
    gsrc += 3 * tadv;

    for (int tile = 0; tile < ntiles; ++tile) {
        if (tile + 1 < ntiles) {
            *(float4*)(slot0 + (((tile + 1) & 1) << 8)) = rA;  // stage next
            rA = rB;
            if (tile + 3 < ntiles) {                            // keep 2 in flight
                rB = *(const float4*)gsrc;
                gsrc += tadv;
            }
        }
        const float* tb = &tiles[wid][tile & 1][0][0] + c;
#pragma unroll
        for (int s = 0; s < TSTEP; ++s) {
            float uv = tb[s << 4];          // broadcast ds_read_b32
#pragma unroll
            for (int k = 0; k < 16; ++k)
                z[k] = fmaf(a[k], z[k], uv);
        }
    }

    float* Sp = S + (((size_t)g * BATCH + b) * DM + d) * NS + n0;
    float4* Sp4 = (float4*)Sp;
#pragma unroll
    for (int j = 0; j < 4; ++j)
        Sp4[j] = make_float4(z[4 * j], z[4 * j + 1], z[4 * j + 2], z[4 * j + 3]);
}

// ---------------- pass 3 (with folded lookback) ----------------
__global__ __launch_bounds__(256, 2)
void pass3_kernel(const float* __restrict__ u,
                  const float* __restrict__ log_dt,
                  const float* __restrict__ A_real,
                  const float* __restrict__ B,
                  const float* __restrict__ Cm,
                  const float* __restrict__ S,
                  const float* __restrict__ x0,
                  float* __restrict__ y, int Tc, int C) {
    __shared__ float tiles[4][2][TSTEP][16];
    int wid  = threadIdx.x >> 6;
    int lane = threadIdx.x & 63;
    int wave = (blockIdx.x * blockDim.x + threadIdx.x) >> 6;
    int w  = wave & 511;
    int g  = wave >> 9;
    int b  = w >> 4;
    int d0 = (w & 15) << 4;
    int c   = lane >> 2;
    int sub = lane & 3;
    int d   = d0 + c;
    int n0  = sub << 4;

    float dt = expf(log_dt[d]);
    const float* Ap = A_real + d * NS + n0;
    const float* Bp = B + d * NS + n0;
    float a[16], z[16];
#pragma unroll
    for (int k = 0; k < 16; ++k)
        a[k] = expf(Ap[k] * dt);

    // z-init from x0 (z = x0 / B_tilde, guarded; zero in the bench case)
#pragma unroll
    for (int k = 0; k < 16; ++k) {
        float x0v = x0[d * NS + n0 + k];
        if (x0v == 0.0f) { z[k] = 0.0f; }
        else {
            float bt = (1.0f - a[k]) * Bp[k] / Ap[k];
            z[k] = (bt != 0.0f) ? (x0v / bt) : 0.0f;
        }
    }

    // in-register lookback: z = aT*z + E_h for h = 0..g-1 (== old pass2 math)
    if (g > 0) {
        float aT[16];
        float dTc = dt * (float)Tc;
#pragma unroll
        for (int k = 0; k < 16; ++k)
            aT[k] = expf(Ap[k] * dTc);          // a^Tc
        const size_t estride = (size_t)BATCH * DM * NS;
        const float* Eb = S + ((size_t)b * DM + d) * NS + n0;
        for (int h = 0; h < g; ++h) {
            const float4* E4 = (const float4*)(Eb + (size_t)h * estride);
            float4 e0 = E4[0], e1 = E4[1], e2 = E4[2], e3 = E4[3];
            z[0]  = fmaf(aT[0],  z[0],  e0.x); z[1]  = fmaf(aT[1],  z[1],  e0.y);
            z[2]  = fmaf(aT[2],  z[2],  e0.z); z[3]  = fmaf(aT[3],  z[3],  e0.w);
            z[4]  = fmaf(aT[4],  z[4],  e1.x); z[5]  = fmaf(aT[5],  z[5],  e1.y);
            z[6]  = fmaf(aT[6],  z[6],  e1.z); z[7]  = fmaf(aT[7],  z[7],  e1.w);
            z[8]  = fmaf(aT[8],  z[8],  e2.x); z[9]  = fmaf(aT[9],  z[9],  e2.y);
            z[10] = fmaf(aT[10], z[10], e2.z); z[11] = fmaf(aT[11], z[11], e2.w);
            z[12] = fmaf(aT[12], z[12], e3.x); z[13] = fmaf(aT[13], z[13], e3.y);
            z[14] = fmaf(aT[14], z[14], e3.z); z[15] = fmaf(aT[15], z[15], e3.w);
        }
    }

    // cbt computed AFTER the lookback so aT's registers are dead here
    float cbt[16];
    {
        const float* Cp = Cm + d * NS + n0;
#pragma unroll
        for (int k = 0; k < 16; ++k)
            cbt[k] = Cp[k] * ((1.0f - a[k]) * Bp[k] / Ap[k]);  // C * B_tilde
    }

    const float* gsrc = u + (size_t)b * SEQ * DM + (size_t)(g * Tc) * DM
                        + (size_t)(lane >> 2) * DM + d0 + ((lane & 3) << 2);
    const size_t tadv = (size_t)TSTEP * DM;
    float* slot0 = &tiles[wid][0][0][0] + (lane << 2);
    const int ntiles = Tc / TSTEP;
    float* yptr = y + (size_t)b * SEQ * DM + (size_t)(g * Tc) * DM + d;

    float4 rnext = *(const float4*)gsrc;
    *(float4*)slot0 = rnext;
    gsrc += tadv;
    rnext = *(const float4*)gsrc;
    gsrc += tadv;

    for (int tile = 0; tile < ntiles; ++tile) {
        int cur = tile & 1;
        if (tile + 1 < ntiles)
            *(float4*)(slot0 + (((tile + 1) & 1) << 8)) = rnext;
        if (tile + 2 < ntiles) {
            rnext = *(const float4*)gsrc;
            gsrc += tadv;
        }
        const float* tb = &tiles[wid][cur][0][0] + c;
#pragma unroll
        for (int s = 0; s < TSTEP; ++s) {
            float uv = tb[s << 4];              // broadcast ds_read_b32
            float p0 = 0.0f, p1 = 0.0f;
#pragma unroll
            for (int k = 0; k < 16; k += 2) {
                z[k]   = fmaf(a[k],   z[k],   uv); p0 = fmaf(cbt[k],   z[k],   p0);
                z[k+1] = fmaf(a[k+1], z[k+1], uv); p1 = fmaf(cbt[k+1], z[k+1], p1);
            }
            float p = p0 + p1;
            p += __shfl_xor(p, 1);   // combine the four quarter-state partials
            p += __shfl_xor(p, 2);
            if (sub == 0) yptr[s * DM] = p;  // imm-offset store
        }
        yptr += tadv;
    }
}

extern "C" void kernel_launch(void* const* d_in, const int* in_sizes, int n_in,
                              void* d_out, int out_size, void* d_ws, size_t ws_size,
                              hipStream_t stream) {
    const float* u      = (const float*)d_in[0];
    const float* log_dt = (const float*)d_in[1];
    const float* A_real = (const float*)d_in[2];
    const float* B      = (const float*)d_in[3];
    const float* Cm     = (const float*)d_in[4];
    const float* x0     = (const float*)d_in[5];
    float* y = (float*)d_out;
    float* S = (float*)d_ws;

    const size_t per_chunk = (size_t)BATCH * DM * NS * sizeof(float);  // 2 MB
    int C = 16;
    while (C > 1 && (size_t)(C - 1) * per_chunk > ws_size) C >>= 1;
    if ((size_t)(C - 1) * per_chunk > ws_size) C = 1;
    int Tc = SEQ / C;

    if (C > 1) {
        // chunks 0..C-2 publish end-states; 512 waves/chunk, 4 waves/block
        pass1_kernel<<<dim3((C - 1) * 128), dim3(256), 0, stream>>>(
            u, log_dt, A_real, S, Tc);
    }
    pass3_kernel<<<dim3(C * 128), dim3(256), 0, stream>>>(
        u, log_dt, A_real, B, Cm, S, x0, y, Tc, C);
}